// Round 14
// baseline (338.760 us; speedup 1.0000x reference)
//
#include <hip/hip_runtime.h>

typedef unsigned short u16;
typedef unsigned int u32;
typedef __attribute__((ext_vector_type(4))) float floatx4;
typedef __attribute__((ext_vector_type(16))) float floatx16;
typedef __attribute__((ext_vector_type(8))) __bf16 bf16x8;

#define MFMA_BF16(a, b, c) __builtin_amdgcn_mfma_f32_16x16x32_bf16((a), (b), (c), 0, 0, 0)
#define MFMA32_BF16(a, b, c) __builtin_amdgcn_mfma_f32_32x32x16_bf16((a), (b), (c), 0, 0, 0)

typedef const __attribute__((address_space(1))) void* gas_ptr;
typedef __attribute__((address_space(3))) void* las_ptr;

__device__ __forceinline__ void gll16(const void* g, void* l) {
  __builtin_amdgcn_global_load_lds((gas_ptr)g, (las_ptr)l, 16, 0, 0);
}

__device__ __forceinline__ u16 f2bf(float x) {
  u32 u = __builtin_bit_cast(u32, x);
  u = (u + 0x7fffu + ((u >> 16) & 1u)) >> 16;
  return (u16)u;
}

// ---------------------------------------------------------------------------
// Kernel 1: down/up vectors from palette.  (R11 verbatim)
// ---------------------------------------------------------------------------
__global__ void prep_downup(const float* __restrict__ pal,
                            const float* __restrict__ qd, const float* __restrict__ qu,
                            const float* __restrict__ kd, const float* __restrict__ ku,
                            const float* __restrict__ vd, const float* __restrict__ vu,
                            const float* __restrict__ od, const float* __restrict__ ou,
                            float* __restrict__ down_f, float* __restrict__ up_f) {
  int tid = blockIdx.x * blockDim.x + threadIdx.x;
  int w = tid / 10240;
  int rem = tid - w * 10240;
  const float* dsrc = (w == 0) ? qd : (w == 1) ? kd : (w == 2) ? vd : od;
  const float* usrc = (w == 0) ? qu : (w == 1) ? ku : (w == 2) ? vu : ou;
  bool isdown = rem < 5120;
  int row = isdown ? rem : rem - 5120;
  const float* src = (isdown ? dsrc : usrc) + row * 15;
  float s = 0.f;
#pragma unroll
  for (int p = 0; p < 15; ++p) s += pal[p] * src[p];
  if (isdown) down_f[w * 5120 + row] = s;
  else        up_f[w * 5120 + row] = s;
}

// ---------------------------------------------------------------------------
// Kernel 2: W_eff = W + up*down, cast to bf16.  (R11 verbatim)
// ---------------------------------------------------------------------------
__global__ void build_weff(const float* __restrict__ Wq, const float* __restrict__ Wk,
                           const float* __restrict__ Wv, const float* __restrict__ Wo,
                           const float* __restrict__ down_f, const float* __restrict__ up_f,
                           u16* __restrict__ weff_qkv, u16* __restrict__ weff_o) {
  int tid = blockIdx.x * blockDim.x + threadIdx.x;  // 4 * 1638400
  int w = tid / 1638400;
  int rem = tid - w * 1638400;
  int n = rem / 1280;
  int k = rem - n * 1280;
  const float* W = (w == 0) ? Wq : (w == 1) ? Wk : (w == 2) ? Wv : Wo;
  const float* up = up_f + w * 5120 + n * 4;
  const float* dn = down_f + w * 5120 + k;
  float v = W[rem] + up[0] * dn[0] + up[1] * dn[1280] + up[2] * dn[2560] + up[3] * dn[3840];
  u16 hv = f2bf(v);
  if (w < 3) weff_qkv[w * 1638400 + rem] = hv;
  else       weff_o[rem] = hv;
}

// ---------------------------------------------------------------------------
// Kernel 3: x fp32 -> bf16  (R11 verbatim)
// ---------------------------------------------------------------------------
__global__ void cvt_x(const float4* __restrict__ x, ushort4* __restrict__ xb) {
  int i = blockIdx.x * blockDim.x + threadIdx.x;  // 1310720
  float4 v = x[i];
  ushort4 o;
  o.x = f2bf(v.x); o.y = f2bf(v.y); o.z = f2bf(v.z); o.w = f2bf(v.w);
  xb[i] = o;
}

// ---------------------------------------------------------------------------
// QKV GEMM: 128x128 tile, BK=64, rotate-by-row swizzle (R11 verbatim —
// the 301.8 µs config; 256-tile variant measured slower, R13).
// ---------------------------------------------------------------------------
__global__ __launch_bounds__(256) void gemm128_qkv(const u16* __restrict__ A, const u16* __restrict__ Bm,
                                                   u16* __restrict__ qb, u16* __restrict__ kb,
                                                   u16* __restrict__ vbuf, int K) {
  __shared__ __align__(16) u16 lA[128 * 64];
  __shared__ __align__(16) u16 lB[128 * 64];
  const int t = threadIdx.x;
  const int lane = t & 63;
  const int l15 = lane & 15, quad = lane >> 4;
  const int wid = t >> 6;
  const int wm = (wid >> 1) * 64;
  const int wn = (wid & 1) * 64;
  const int bm = blockIdx.x * 128;
  const int bn = blockIdx.y * 128;
  floatx4 acc[4][4] = {};

  int soff[4];
#pragma unroll
  for (int i = 0; i < 4; ++i) {
    int c = t + i * 256;
    int row = c >> 3, pos = c & 7;
    soff[i] = row * K + ((pos + row) & 7) * 8;
  }
  int afo[4][2], bfo[4][2];
#pragma unroll
  for (int i = 0; i < 4; ++i) {
#pragma unroll
    for (int ch = 0; ch < 2; ++ch) {
      int ra = wm + i * 16 + l15;
      int rb = wn + i * 16 + l15;
      int kc8 = ch * 4 + quad;
      afo[i][ch] = ra * 64 + ((kc8 - ra) & 7) * 8;
      bfo[i][ch] = rb * 64 + ((kc8 - rb) & 7) * 8;
    }
  }

  const u16* Ab = A + (long)bm * K;
  const u16* Bb = Bm + (long)bn * K;
  const int nkt = K >> 6;

  for (int kt = 0; kt < nkt; ++kt) {
    __syncthreads();
    const int k0 = kt * 64;
#pragma unroll
    for (int i = 0; i < 4; ++i) gll16(Ab + (long)soff[i] + k0, lA + (t + i * 256) * 8);
#pragma unroll
    for (int i = 0; i < 4; ++i) gll16(Bb + (long)soff[i] + k0, lB + (t + i * 256) * 8);
    __syncthreads();
#pragma unroll
    for (int ch = 0; ch < 2; ++ch) {
      bf16x8 af[4], bfr[4];
#pragma unroll
      for (int i = 0; i < 4; ++i) af[i] = *(const bf16x8*)(lA + afo[i][ch]);
#pragma unroll
      for (int i = 0; i < 4; ++i) bfr[i] = *(const bf16x8*)(lB + bfo[i][ch]);
#pragma unroll
      for (int i = 0; i < 4; ++i)
#pragma unroll
        for (int j = 0; j < 4; ++j)
          acc[i][j] = MFMA_BF16(af[i], bfr[j], acc[i][j]);
    }
  }

#pragma unroll
  for (int i = 0; i < 4; ++i) {
#pragma unroll
    for (int j = 0; j < 4; ++j) {
#pragma unroll
      for (int r = 0; r < 4; ++r) {
        int m = bm + wm + i * 16 + quad * 4 + r;
        int n = bn + wn + j * 16 + l15;
        u16 hv = f2bf(acc[i][j][r]);
        if (n < 1280) {
          qb[(long)m * 1280 + n] = hv;
        } else if (n < 2560) {
          kb[(long)m * 1280 + (n - 1280)] = hv;
        } else {
          vbuf[(long)m * 1280 + (n - 2560)] = hv;
        }
      }
    }
  }
}

// ---------------------------------------------------------------------------
// V transpose (scalar, VERIFIED R10/R11/R13 — do not touch).
// ---------------------------------------------------------------------------
__global__ __launch_bounds__(256) void vtrans(const u16* __restrict__ vbuf,
                                              u16* __restrict__ vtb) {
  __shared__ u16 tile[64 * 65];
  const int t = threadIdx.x;
  const int sb = blockIdx.x * 64, nb = blockIdx.y * 64, b = blockIdx.z;
  const u16* src = vbuf + ((long)(b * 2048 + sb)) * 1280 + nb;
#pragma unroll
  for (int it = 0; it < 16; ++it) {
    int idx = t + it * 256;
    int s = idx >> 6, n = idx & 63;
    tile[s * 65 + n] = src[(long)s * 1280 + n];
  }
  __syncthreads();
  u16* dst = vtb + ((long)(b * 1280 + nb)) * 2048 + sb;
#pragma unroll
  for (int it = 0; it < 16; ++it) {
    int idx = t + it * 256;
    int n = idx >> 6, s = idx & 63;
    dst[(long)n * 2048 + s] = tile[s * 65 + n];
  }
}

// ---------------------------------------------------------------------------
// O-proj GEMM: 64x128 tile, BK=64 (R11 verbatim).
// ---------------------------------------------------------------------------
__global__ __launch_bounds__(256) void gemm64_o(const u16* __restrict__ A, const u16* __restrict__ Bm,
                                                float* __restrict__ outf,
                                                const float* __restrict__ bias, int K) {
  __shared__ __align__(16) u16 lA[64 * 64];
  __shared__ __align__(16) u16 lB[128 * 64];
  const int t = threadIdx.x;
  const int lane = t & 63;
  const int l15 = lane & 15, quad = lane >> 4;
  const int wid = t >> 6;
  const int bm = blockIdx.x * 64;
  const int bn = blockIdx.y * 128;
  floatx4 acc[4][2] = {};

  int aoff[2], boff[4];
#pragma unroll
  for (int i = 0; i < 2; ++i) {
    int c = t + i * 256;
    int row = c >> 3, pos = c & 7;
    aoff[i] = row * K + ((pos + row) & 7) * 8;
  }
#pragma unroll
  for (int i = 0; i < 4; ++i) {
    int c = t + i * 256;
    int row = c >> 3, pos = c & 7;
    boff[i] = row * K + ((pos + row) & 7) * 8;
  }
  int afo[4][2], bfo[2][2];
#pragma unroll
  for (int ch = 0; ch < 2; ++ch) {
    int kc8 = ch * 4 + quad;
#pragma unroll
    for (int i = 0; i < 4; ++i) {
      int ra = i * 16 + l15;
      afo[i][ch] = ra * 64 + ((kc8 - ra) & 7) * 8;
    }
#pragma unroll
    for (int j = 0; j < 2; ++j) {
      int rb = wid * 32 + j * 16 + l15;
      bfo[j][ch] = rb * 64 + ((kc8 - rb) & 7) * 8;
    }
  }

  const u16* Ab = A + (long)bm * K;
  const u16* Bb = Bm + (long)bn * K;
  const int nkt = K >> 6;

  for (int kt = 0; kt < nkt; ++kt) {
    __syncthreads();
    const int k0 = kt * 64;
#pragma unroll
    for (int i = 0; i < 2; ++i) gll16(Ab + (long)aoff[i] + k0, lA + (t + i * 256) * 8);
#pragma unroll
    for (int i = 0; i < 4; ++i) gll16(Bb + (long)boff[i] + k0, lB + (t + i * 256) * 8);
    __syncthreads();
#pragma unroll
    for (int ch = 0; ch < 2; ++ch) {
      bf16x8 af[4], bfr[2];
#pragma unroll
      for (int i = 0; i < 4; ++i) af[i] = *(const bf16x8*)(lA + afo[i][ch]);
#pragma unroll
      for (int j = 0; j < 2; ++j) bfr[j] = *(const bf16x8*)(lB + bfo[j][ch]);
#pragma unroll
      for (int i = 0; i < 4; ++i)
#pragma unroll
        for (int j = 0; j < 2; ++j)
          acc[i][j] = MFMA_BF16(af[i], bfr[j], acc[i][j]);
    }
  }

#pragma unroll
  for (int i = 0; i < 4; ++i) {
#pragma unroll
    for (int j = 0; j < 2; ++j) {
#pragma unroll
      for (int r = 0; r < 4; ++r) {
        int m = bm + i * 16 + quad * 4 + r;
        int n = bn + wid * 32 + j * 16 + l15;
        outf[(long)m * 1280 + n] = acc[i][j][r] + bias[n];
      }
    }
  }
}

// ---------------------------------------------------------------------------
// Flash attention v8 — 32x32x16 MFMAs (2x FLOP per fragment byte: directly
// halves the LDS-read traffic that bounds v3).  Grid (32,16), 256 thr =
// 4 waves: qsub=wid&1 (32 q-rows), kh=wid>>1 (in-block key-split: 32 keys of
// each 64-key tile).  Staging + kt/vt swizzles verbatim v3 (verified).
// Fixed-base softmax -> key-half partials additive; merged via LDS epilogue
// (v7-verified pattern).  32x32 C/D: col=lane&31, row=(reg&3)+8(reg>>2)+
// 4(lane>>5) [HW-verified m74/m101].  A/B: m|n=lane&31, k=(lane>>5)*8+j.
// LDS 51.2 KB + epilogue aliased at 0.
// ---------------------------------------------------------------------------
__global__ __launch_bounds__(256) void flash_attn(const u16* __restrict__ qb,
                                                  const u16* __restrict__ kb,
                                                  const u16* __restrict__ vtb,
                                                  u16* __restrict__ attn) {
  const int S = 2048, D = 1280, HD = 160;
  __shared__ __align__(16) u16 sh[25600];  // kt@0(10240) vt@10240(10240) p@20480(4x1280)
  __shared__ float l_sh[64];
  u16* kt_lds = sh;
  u16* vt_lds = sh + 10240;
  const int t = threadIdx.x, lane = t & 63, wid = t >> 6;
  const int l31 = lane & 31, half = lane >> 5;
  const int bh = blockIdx.y, b = bh >> 3, h = bh & 7;
  const int qsub = wid & 1, kh = wid >> 1;
  const int q0 = blockIdx.x * 64 + qsub * 32;
  const float kS = 0.11404582025f;  // (1/sqrt(160)) * log2(e)
  u16* p_my = sh + 20480 + wid * 1280;  // 32 rows x 40 u16

  // Q A-frags: Q[q0+l31][h*160 + dc*16 + half*8 + j]
  bf16x8 aq[10];
  {
    const u16* qg = qb + ((long)(b * 2048 + q0 + l31)) * D + h * HD + half * 8;
#pragma unroll
    for (int dc = 0; dc < 10; ++dc) aq[dc] = *(const bf16x8*)(qg + dc * 16);
  }

  // Staging source pointers (v3 verbatim; all 4 waves stage the full tile).
  const u16* kg[5];
  const u16* vg[5];
  {
    const u16* kgbase = kb + ((long)(b * 2048)) * D + h * HD;
    const u16* vgbase = vtb + ((long)(b * 1280 + h * HD)) * 2048;
#pragma unroll
    for (int i = 0; i < 5; ++i) {
      int c = t + i * 256;
      int key = c / 20, rot = c - key * 20;
      int ccol = rot - (key % 20);
      if (ccol < 0) ccol += 20;
      kg[i] = kgbase + (long)key * D + ccol * 8;
      int vrow = c >> 3, swz = c & 7;
      int vcol = swz ^ (vrow & 7);
      vg[i] = vgbase + (long)vrow * 2048 + vcol * 8;
    }
  }

  // kf offsets: B-frag K[key = kh*32+l31][d-chunk c20 = dc*2 + half],
  // rotated layout: chunk g of row r sits at position (g + r) % 20.
  int kfo[10];
  {
    int keyrow = kh * 32 + l31;
#pragma unroll
    for (int dc = 0; dc < 10; ++dc) {
      int c20 = dc * 2 + half;
      int pos = c20 + keyrow % 20;
      pos = (c20 + keyrow) % 20;
      kfo[dc] = (keyrow * 20 + pos) * 8;
    }
  }
  // vf offsets: B-frag Vt[d = ng*32+l31][key-chunk = kh*4 + kc*2 + half],
  // XOR layout: chunk g of row r sits at position g ^ (r & 7).
  int vfo[5][2];
#pragma unroll
  for (int ng = 0; ng < 5; ++ng) {
    int row = ng * 32 + l31;
#pragma unroll
    for (int kc = 0; kc < 2; ++kc) {
      int sw = (kh * 4 + kc * 2 + half) ^ (row & 7);
      vfo[ng][kc] = (row * 8 + sw) * 8;
    }
  }

  float l_part[16];
#pragma unroll
  for (int r = 0; r < 16; ++r) l_part[r] = 0.f;
  floatx16 o_acc[5] = {};

  for (int kt0 = 0; kt0 < S; kt0 += 64) {
    __syncthreads();
#pragma unroll
    for (int i = 0; i < 5; ++i) gll16(kg[i], kt_lds + (t + i * 256) * 8);
#pragma unroll
    for (int i = 0; i < 5; ++i) gll16(vg[i], vt_lds + (t + i * 256) * 8);
#pragma unroll
    for (int i = 0; i < 5; ++i) { kg[i] += (long)64 * D; vg[i] += 64; }
    __syncthreads();

    // QK^T: 32 q-rows x 32 keys (this wave's key-half).
    floatx16 s = {};
#pragma unroll
    for (int dc = 0; dc < 10; ++dc) {
      bf16x8 kf = *(const bf16x8*)(kt_lds + kfo[dc]);
      s = MFMA32_BF16(aq[dc], kf, s);
    }

    // Fixed-base softmax numerator; P -> per-wave LDS (stride 40, [m][k]).
#pragma unroll
    for (int reg = 0; reg < 16; ++reg) {
      int row = (reg & 3) + 8 * (reg >> 2) + 4 * half;
      float p = __builtin_exp2f(fminf(s[reg] * kS, 80.f));
      l_part[reg] += p;
      p_my[row * 40 + l31] = f2bf(p);
    }
    asm volatile("s_waitcnt lgkmcnt(0)" ::: "memory");  // wave-local P visibility

    // PV: A = P[m=l31][k = kc*16 + half*8 + j], B = Vt fragments.
    bf16x8 pa0 = *(const bf16x8*)(p_my + l31 * 40 + half * 8);
    bf16x8 pa1 = *(const bf16x8*)(p_my + l31 * 40 + 16 + half * 8);
#pragma unroll
    for (int ng = 0; ng < 5; ++ng) {
      bf16x8 vf0 = *(const bf16x8*)(vt_lds + vfo[ng][0]);
      bf16x8 vf1 = *(const bf16x8*)(vt_lds + vfo[ng][1]);
      o_acc[ng] = MFMA32_BF16(pa0, vf0, o_acc[ng]);
      o_acc[ng] = MFMA32_BF16(pa1, vf1, o_acc[ng]);
    }
  }

  // Reduce l across the 32 key-columns (butterfly within each half-group).
  float l_red[16];
#pragma unroll
  for (int reg = 0; reg < 16; ++reg) {
    float rs = l_part[reg];
    rs += __shfl_xor(rs, 1, 64);
    rs += __shfl_xor(rs, 2, 64);
    rs += __shfl_xor(rs, 4, 64);
    rs += __shfl_xor(rs, 8, 64);
    rs += __shfl_xor(rs, 16, 64);
    l_red[reg] = rs;
  }

  // Merge key-halves through LDS (o_sh aliased over kt/vt, stride 168).
  __syncthreads();
  if (kh == 1) {
#pragma unroll
    for (int reg = 0; reg < 16; ++reg) {
      int row = (reg & 3) + 8 * (reg >> 2) + 4 * half;
      int rl = qsub * 32 + row;
      if (l31 == 0) l_sh[rl] = l_red[reg];
#pragma unroll
      for (int ng = 0; ng < 5; ++ng)
        sh[rl * 168 + ng * 32 + l31] = f2bf(o_acc[ng][reg]);
    }
  }
  __syncthreads();
  if (kh == 0) {
#pragma unroll
    for (int reg = 0; reg < 16; ++reg) {
      int row = (reg & 3) + 8 * (reg >> 2) + 4 * half;
      int rl = qsub * 32 + row;
      float inv = 1.0f / (l_red[reg] + l_sh[rl]);
      long grow = (long)(b * 2048 + blockIdx.x * 64 + rl);
#pragma unroll
      for (int ng = 0; ng < 5; ++ng) {
        float other = (float)__builtin_bit_cast(__bf16, sh[rl * 168 + ng * 32 + l31]);
        float v = (o_acc[ng][reg] + other) * inv;
        attn[grow * D + h * HD + ng * 32 + l31] = f2bf(v);
      }
    }
  }
}

// ---------------------------------------------------------------------------
// Launcher.  Workspace (~76.2 MB):
//   xb @0 | weff_qkv @10485760 | weff_o @20316160 | qbuf @23592960
//   kbuf @34078720 | vtb @44564480 | attn @55050240 | down_f @65536000
//   up_f @65617920 | vbuf @65699840
// ---------------------------------------------------------------------------
extern "C" void kernel_launch(void* const* d_in, const int* in_sizes, int n_in,
                              void* d_out, int out_size, void* d_ws, size_t ws_size,
                              hipStream_t stream) {
  const float* x   = (const float*)d_in[0];
  const float* pal = (const float*)d_in[1];
  const float* Wq  = (const float*)d_in[2];
  const float* Wk  = (const float*)d_in[3];
  const float* Wv  = (const float*)d_in[4];
  const float* Wo  = (const float*)d_in[5];
  const float* bo  = (const float*)d_in[6];
  const float* qd  = (const float*)d_in[7];
  const float* qu  = (const float*)d_in[8];
  const float* kd  = (const float*)d_in[9];
  const float* ku  = (const float*)d_in[10];
  const float* vd  = (const float*)d_in[11];
  const float* vu  = (const float*)d_in[12];
  const float* od  = (const float*)d_in[13];
  const float* ou  = (const float*)d_in[14];
  float* out = (float*)d_out;

  char* ws = (char*)d_ws;
  u16* xb       = (u16*)(ws);
  u16* weff_qkv = (u16*)(ws + 10485760);
  u16* weff_o   = (u16*)(ws + 20316160);
  u16* qbuf     = (u16*)(ws + 23592960);
  u16* kbuf     = (u16*)(ws + 34078720);
  u16* vtb      = (u16*)(ws + 44564480);
  u16* attn     = (u16*)(ws + 55050240);
  float* down_f = (float*)(ws + 65536000);
  float* up_f   = (float*)(ws + 65617920);
  u16* vbuf     = (u16*)(ws + 65699840);

  prep_downup<<<160, 256, 0, stream>>>(pal, qd, qu, kd, ku, vd, vu, od, ou, down_f, up_f);
  build_weff<<<25600, 256, 0, stream>>>(Wq, Wk, Wv, Wo, down_f, up_f, weff_qkv, weff_o);
  cvt_x<<<5120, 256, 0, stream>>>((const float4*)x, (ushort4*)xb);
  gemm128_qkv<<<dim3(32, 30), 256, 0, stream>>>(xb, weff_qkv, qbuf, kbuf, vbuf, 1280);
  vtrans<<<dim3(32, 20, 2), 256, 0, stream>>>(vbuf, vtb);
  flash_attn<<<dim3(32, 16), 256, 0, stream>>>(qbuf, kbuf, vtb, attn);
  gemm64_o<<<dim3(64, 10), 256, 0, stream>>>(attn, weff_o, out, bo, 1280);
}